// Round 6
// baseline (140.217 us; speedup 1.0000x reference)
//
#include <hip/hip_runtime.h>
#include <math.h>

typedef __bf16 v8bf __attribute__((ext_vector_type(8)));
typedef float  v4f  __attribute__((ext_vector_type(4)));

constexpr int Bsz  = 8;
constexpr int Cch  = 32;
constexpr int WIMG = 128;
constexpr int OH   = 64;
constexpr int OW   = 64;
constexpr int INCH = 201;
constexpr int KP   = 224;
constexpr int NK   = 7;
constexpr int OUTCH = 1152;
constexpr int MTOT = Bsz * OH * OW;   // 32768
constexpr float BN_EPS = 1e-5f;

// ws layout
constexpr size_t WT_BYTES = (size_t)NK * OUTCH * 32 * 2;   // 516,096
constexpr size_t BIAS_OFF = WT_BYTES;
constexpr size_t FEAT_OFF = BIAS_OFF + OUTCH * 4;          // 520,704 (16-aligned)

// ---- async global->LDS (wave-uniform base + lane*16 contiguous) ----
typedef const void __attribute__((address_space(1)))* gas_ptr;
typedef void __attribute__((address_space(3)))* las_ptr;
__device__ __forceinline__ void load16_lds(const void* g, void* l) {
    __builtin_amdgcn_global_load_lds((gas_ptr)(uintptr_t)g, (las_ptr)(uintptr_t)l, 16, 0, 0);
}

// ---------------------------------------------------------------------------
// K1: fused prep (blocks >= 512) + feat (blocks 0..511).  (unchanged from R5)
// ---------------------------------------------------------------------------
constexpr int SXS = 132;            // padded sx row stride (floats)
constexpr int FEAT_BLOCKS = Bsz * OH;        // 512
constexpr int NPREP = OUTCH * KP + OUTCH;    // 259,200
constexpr int PREP_BLOCKS = (NPREP + 255) / 256;

__global__ __launch_bounds__(256)
void prep_feat_kernel(const float* __restrict__ x,
                      const float* __restrict__ conv_w,
                      const float* __restrict__ gamma,
                      const float* __restrict__ beta,
                      const float* __restrict__ mean,
                      const float* __restrict__ var,
                      __bf16* __restrict__ Wt,
                      float* __restrict__ biasp,
                      __bf16* __restrict__ feat) {
    __shared__ __align__(16) float sx[Cch * 3 * SXS];     // 50,688 B
    __shared__ __align__(16) float cmax[3 * SXS];         //  1,584 B
    __shared__ __align__(16) __bf16 sfeat[NK * OW * 32];  // 28,672 B

    const int t = threadIdx.x;

    if (blockIdx.x >= FEAT_BLOCKS) {
        int idx = ((int)blockIdx.x - FEAT_BLOCKS) * 256 + t;
        const int nW = OUTCH * KP;
        if (idx < nW) {
            int o = idx / KP;
            int f = idx - o * KP;
            float inv = gamma[o] * rsqrtf(var[o] + BN_EPS);
            float v = (f < INCH) ? conv_w[o * INCH + f] * inv : 0.0f;
            Wt[((size_t)(f >> 5) * OUTCH + o) * 32 + (f & 31)] = (__bf16)v;
        } else if (idx < nW + OUTCH) {
            int o = idx - nW;
            float inv = gamma[o] * rsqrtf(var[o] + BN_EPS);
            biasp[o] = beta[o] - mean[o] * inv;
        }
        return;
    }

    const int b  = blockIdx.x >> 6;
    const int ho = blockIdx.x & 63;

    for (int idx = t; idx < Cch * 3 * 32; idx += 256) {
        int c   = idx / 96;
        int rem = idx - c * 96;
        int i   = rem >> 5;
        int q   = rem & 31;
        int r   = 2 * ho - 1 + i;
        float4 v = make_float4(0.f, 0.f, 0.f, 0.f);
        if (r >= 0 && r < WIMG)
            v = *(const float4*)(x + (((size_t)(b * Cch + c) * WIMG) + r) * WIMG + q * 4);
        float* dst = sx + (c * 3 + i) * SXS + q * 4 + 1;
        dst[0] = v.x; dst[1] = v.y; dst[2] = v.z; dst[3] = v.w;
    }
    if (t < 96) {
        float* row = sx + t * SXS;
        row[0] = 0.0f; row[129] = 0.0f; row[130] = 0.0f; row[131] = 0.0f;
    }
    __syncthreads();

    if (t < 99) {
        int i = t / 33, cg = t - i * 33;
        const float4* base = (const float4*)sx + i * (SXS / 4) + cg;
        float4 m = base[0];
        #pragma unroll 4
        for (int c = 1; c < Cch; ++c) {
            float4 v = base[(size_t)c * (3 * SXS / 4)];
            m.x = fmaxf(m.x, v.x); m.y = fmaxf(m.y, v.y);
            m.z = fmaxf(m.z, v.z); m.w = fmaxf(m.w, v.w);
        }
        ((float4*)cmax)[i * (SXS / 4) + cg] = m;
    }
    __syncthreads();

    for (int idx = t; idx < 9 * 64; idx += 256) {
        int f = idx >> 6, wo = idx & 63;
        int i = f / 3, j = f - 3 * i;
        sfeat[wo * 32 + f] = (__bf16)cmax[i * SXS + 2 * wo + j];
    }
    {
        const int wp = t & 31, g = t >> 5;
        const int wo0 = 2 * wp;
        #pragma unroll
        for (int cl = 0; cl < 4; ++cl) {
            int c = g * 4 + cl;
            float v[3][5];
            #pragma unroll
            for (int i = 0; i < 3; ++i) {
                const float* row = sx + (c * 3 + i) * SXS + 4 * wp;
                float4 q = *(const float4*)row;
                v[i][0] = q.x; v[i][1] = q.y; v[i][2] = q.z; v[i][3] = q.w;
                v[i][4] = row[4];
            }
            #pragma unroll
            for (int i = 0; i < 3; ++i) {
                int f = 105 + c * 3 + i;
                float a0 = fmaxf(fmaxf(v[i][0], v[i][1]), v[i][2]);
                float a1 = fmaxf(fmaxf(v[i][2], v[i][3]), v[i][4]);
                sfeat[(f >> 5) * 2048 + wo0 * 32 + (f & 31)]       = (__bf16)a0;
                sfeat[(f >> 5) * 2048 + (wo0 + 1) * 32 + (f & 31)] = (__bf16)a1;
            }
            #pragma unroll
            for (int j = 0; j < 3; ++j) {
                int f = 9 + c * 3 + j;
                float a0 = fmaxf(fmaxf(v[0][j], v[1][j]), v[2][j]);
                float a1 = fmaxf(fmaxf(v[0][j + 2], v[1][j + 2]), v[2][j + 2]);
                sfeat[(f >> 5) * 2048 + wo0 * 32 + (f & 31)]       = (__bf16)a0;
                sfeat[(f >> 5) * 2048 + (wo0 + 1) * 32 + (f & 31)] = (__bf16)a1;
            }
        }
    }
    for (int idx = t; idx < 64 * 23; idx += 256) {
        int wo = idx / 23, fo = idx - wo * 23;
        int f = 201 + fo;
        sfeat[6 * 2048 + wo * 32 + (f & 31)] = (__bf16)0.0f;
    }
    __syncthreads();

    const size_t spat0 = (size_t)(b * OH + ho) * OW;
    #pragma unroll
    for (int kc = 0; kc < NK; ++kc) {
        float4 vv = ((const float4*)sfeat)[kc * 256 + t];
        ((float4*)((char*)feat + ((size_t)kc * MTOT + spat0) * 64))[t] = vv;
    }
}

// ---------------------------------------------------------------------------
// K2: gemm v3. Block 384 thr (6 waves = 2M x 3N), tile M=128 x N=144.
//  - B (all 7 k-chunks, 63 KB) -> LDS ONCE via global_load_lds; ZERO barriers
//    in the K-loop.
//  - A fragments loaded global->VGPR directly (no LDS staging; A rows are
//    wave-private), double-buffered 2 ksteps ahead; L2-resident via XCD
//    swizzle (blockIdx = nb*256+mb: same-mb blocks share an XCD).
//  - Per wave per kstep: 3 ds_read_b128 + 4 global_dwordx4 + 12 MFMA.
//  - Epilogue: shared y[128][148] (reuses B region), 512 items / 384 thr.
// LDS 75,776 B -> 2 blocks/CU; ~135 VGPR -> 3 waves/SIMD.
// ---------------------------------------------------------------------------
constexpr int YS = 148;   // y row stride (floats)
__global__ __launch_bounds__(384, 3)
void gemm_kernel(const __bf16* __restrict__ feat,
                 const __bf16* __restrict__ Wt,
                 const float* __restrict__ biasp,
                 const float* __restrict__ x,
                 float* __restrict__ out) {
    __shared__ __align__(16) unsigned char lds[128 * YS * 4];  // 75,776 B

    const int t    = threadIdx.x;
    const int nb   = (int)blockIdx.x >> 8;   // 0..7
    const int mb   = (int)blockIdx.x & 255;  // 0..255
    const int M0   = mb * 128;
    const int N0   = nb * 144;
    const int wave = t >> 6, lane = t & 63, quad = lane >> 4, l16 = lane & 15;
    const int wm   = wave / 3;               // 0..1  (M band of 64)
    const int wn   = wave - 3 * wm;          // 0..2  (N band of 48)

    // ---- stage ALL of B (7 chunks x 9,216 B = 63 chunks of 1 KB) ----
    {
        const char* Bg = (const char*)Wt + (size_t)N0 * 64;
        #pragma unroll
        for (int i = wave; i < 63; i += 6) {
            int ks = i / 9, sub = i - ks * 9;
            load16_lds(Bg + (size_t)ks * (OUTCH * 64) + sub * 1024 + lane * 16,
                       (char*)lds + i * 1024 + lane * 16);
        }
    }

    // ---- A fragment loaders (global -> VGPR, wave-private rows) ----
    const char* Ag = (const char*)feat;
    const int arow0 = M0 + wm * 64 + l16;    // + mt*16
    auto loadA = [&](v8bf (&buf)[4], int ks) {
        #pragma unroll
        for (int mt = 0; mt < 4; ++mt)
            buf[mt] = *(const v8bf*)(Ag +
                ((size_t)ks * MTOT + arow0 + mt * 16) * 64 + quad * 16);
    };
    const char* Bb = (const char*)lds;
    auto loadB = [&](v8bf (&buf)[3], int ks) {
        #pragma unroll
        for (int nt = 0; nt < 3; ++nt)
            buf[nt] = *(const v8bf*)(Bb + ks * 9216 +
                (wn * 48 + nt * 16 + l16) * 64 + quad * 16);
    };

    v4f acc[4][3];
    #pragma unroll
    for (int mt = 0; mt < 4; ++mt)
        #pragma unroll
        for (int nt = 0; nt < 3; ++nt)
            acc[mt][nt] = (v4f){0.f, 0.f, 0.f, 0.f};

    v8bf afA[4], afB[4], bfA[3], bfB[3];
    loadA(afA, 0);
    loadA(afB, 1);
    __syncthreads();          // B staged (drains vmcnt; afA/afB arrive too)
    loadB(bfA, 0);

    auto mfma12 = [&](v8bf (&af)[4], v8bf (&bf)[3]) {
        #pragma unroll
        for (int nt = 0; nt < 3; ++nt)
            #pragma unroll
            for (int mt = 0; mt < 4; ++mt)
                acc[mt][nt] = __builtin_amdgcn_mfma_f32_16x16x32_bf16(
                    af[mt], bf[nt], acc[mt][nt], 0, 0, 0);
    };

    #pragma unroll 1
    for (int ks = 0; ks < 6; ks += 2) {
        loadB(bfB, ks + 1);
        mfma12(afA, bfA);          // kstep ks
        loadA(afA, ks + 2);        // prefetch (ks+2 <= 6)
        loadB(bfA, ks + 2);
        mfma12(afB, bfB);          // kstep ks+1
        if (ks + 3 < NK) loadA(afB, ks + 3);
    }
    mfma12(afA, bfA);              // kstep 6

    // ---- epilogue: y[128][148] in LDS (+bias, ReLU), then dyn-kernel mean ----
    float bia[3];
    #pragma unroll
    for (int nt = 0; nt < 3; ++nt)
        bia[nt] = biasp[N0 + wn * 48 + nt * 16 + l16];

    __syncthreads();               // all waves done reading B region
    float* y = (float*)lds;
    #pragma unroll
    for (int mt = 0; mt < 4; ++mt)
        #pragma unroll
        for (int nt = 0; nt < 3; ++nt)
            #pragma unroll
            for (int r = 0; r < 4; ++r)
                y[(wm * 64 + mt * 16 + quad * 4 + r) * YS + wn * 48 + nt * 16 + l16] =
                    fmaxf(acc[mt][nt][r] + bia[nt], 0.0f);
    __syncthreads();

    const float s9 = 1.0f / 9.0f;
    #pragma unroll
    for (int pass = 0; pass < 2; ++pass) {
        int it = t + pass * 384;
        if (pass == 1 && t >= 128) break;
        const int chl  = it >> 7;            // 0..3
        const int mloc = it & 127;
        const int mg   = M0 + mloc;
        const int bb   = mg >> 12;
        const int hob  = (mg >> 6) & 63;
        const int wo   = mg & 63;
        const int cg   = nb * 4 + chl;
        const float* xc = x + (size_t)(bb * Cch + cg) * WIMG * WIMG;

        float pt[9];
        #pragma unroll
        for (int qi = 0; qi < 3; ++qi) {
            int r = 2 * hob - 1 + qi;
            #pragma unroll
            for (int qj = 0; qj < 3; ++qj) {
                int col = 2 * wo - 1 + qj;
                float v = 0.0f;
                if (r >= 0 && r < WIMG && col >= 0 && col < WIMG)
                    v = xc[r * WIMG + col];
                pt[qi * 3 + qj] = v;
            }
        }
        const float4* yrow = (const float4*)(y + mloc * YS + chl * 36);
        float o00 = 0.f, o01 = 0.f, o10 = 0.f, o11 = 0.f;
        #pragma unroll
        for (int q = 0; q < 9; ++q) {
            float4 yv = yrow[q];
            float pq = pt[q];
            o00 = fmaf(pq, yv.x, o00);
            o01 = fmaf(pq, yv.y, o01);
            o10 = fmaf(pq, yv.z, o10);
            o11 = fmaf(pq, yv.w, o11);
        }
        size_t obase = (((size_t)(bb * Cch + cg) * WIMG) + 2 * hob) * WIMG + 2 * wo;
        *(float2*)(out + obase)        = make_float2(o00 * s9, o01 * s9);
        *(float2*)(out + obase + WIMG) = make_float2(o10 * s9, o11 * s9);
    }
}

extern "C" void kernel_launch(void* const* d_in, const int* in_sizes, int n_in,
                              void* d_out, int out_size, void* d_ws, size_t ws_size,
                              hipStream_t stream) {
    const float* x      = (const float*)d_in[0];
    const float* conv_w = (const float*)d_in[1];
    const float* gamma  = (const float*)d_in[2];
    const float* beta   = (const float*)d_in[3];
    const float* mean   = (const float*)d_in[4];
    const float* var    = (const float*)d_in[5];
    float* out = (float*)d_out;

    __bf16* Wt    = (__bf16*)d_ws;
    float*  biasp = (float*)((char*)d_ws + BIAS_OFF);
    __bf16* feat  = (__bf16*)((char*)d_ws + FEAT_OFF);

    prep_feat_kernel<<<FEAT_BLOCKS + PREP_BLOCKS, 256, 0, stream>>>(
        x, conv_w, gamma, beta, mean, var, Wt, biasp, feat);
    gemm_kernel<<<(OUTCH / 144) * (MTOT / 128), 384, 0, stream>>>(feat, Wt, biasp, x, out);
}